// Round 1
// baseline (586.610 us; speedup 1.0000x reference)
//
#include <hip/hip_runtime.h>

typedef __attribute__((ext_vector_type(4))) float f32x4;
typedef __attribute__((ext_vector_type(16))) float f32x16;
typedef __attribute__((ext_vector_type(4))) unsigned short u16x4;
typedef __attribute__((ext_vector_type(4))) int i32x4;
typedef __attribute__((ext_vector_type(8))) __bf16 bf16x8;

union FragAB {
  u16x4 u[2];
  i32x4 v;
  bf16x8 f;
};

static __device__ __forceinline__ unsigned short f2bf(float x) {
  union { float f; unsigned u; } v;
  v.f = x;
  unsigned r = v.u + 0x7FFFu + ((v.u >> 16) & 1u);  // round-to-nearest-even
  return (unsigned short)(r >> 16);
}

#define NN 8192

// ---------- kernel 1: d_out = bias (broadcast) ----------
__global__ __launch_bounds__(256) void k_bias(const float* __restrict__ bias,
                                              float* __restrict__ out) {
  out[(size_t)blockIdx.x * 256 + threadIdx.x] = bias[threadIdx.x];
}

// ---------- kernel 2: HT[768][8192] = ([w1|w2|w3]^T applied) = (V @ Wcat)^T, bf16 ----
// GEMM M=8192(j) x N=768(3*256) x K=256(c). BM=128, BN=64, BK=32.
// 256 thr = 4 waves, wave grid 2x2, wave tile 64x32, MFMA 16x16x32 bf16.
__global__ __launch_bounds__(256) void k_transform(
    const float* __restrict__ V, const float* __restrict__ w1,
    const float* __restrict__ w2, const float* __restrict__ w3,
    unsigned short* __restrict__ HT) {
  int bx = blockIdx.x;
  int rb = bx & 63;   // j tile of 128
  int nb = bx >> 6;   // 0..11 (64-wide col tile within 768)
  const float* W = (nb < 4) ? w1 : (nb < 8) ? w2 : w3;
  int nc0 = (nb & 3) * 64;
  int tid = threadIdx.x;
  int lane = tid & 63;
  int wv = tid >> 6;
  int wm = wv >> 1, wn = wv & 1;
  int q = lane >> 4, l16 = lane & 15;

  __shared__ unsigned short tA[128][36];  // V tile bf16, padded (72B rows)
  __shared__ unsigned short tB[64][36];   // W tile transposed [n][c]

  f32x4 acc[4][2];
#pragma unroll
  for (int i = 0; i < 4; i++)
#pragma unroll
    for (int j = 0; j < 2; j++) acc[i][j] = (f32x4)0.0f;

  for (int kk = 0; kk < 256; kk += 32) {
    // stage A: V[rb*128 + r][kk + c], r=tid>>1, c0=(tid&1)*16, 16 floats/thread
    {
      int r = tid >> 1, c0 = (tid & 1) * 16;
      const float* src = V + (size_t)(rb * 128 + r) * 256 + kk + c0;
      f32x4 f0 = *(const f32x4*)(src + 0);
      f32x4 f1 = *(const f32x4*)(src + 4);
      f32x4 f2 = *(const f32x4*)(src + 8);
      f32x4 f3 = *(const f32x4*)(src + 12);
      unsigned short* d = &tA[r][c0];
      d[0] = f2bf(f0.x);  d[1] = f2bf(f0.y);  d[2] = f2bf(f0.z);  d[3] = f2bf(f0.w);
      d[4] = f2bf(f1.x);  d[5] = f2bf(f1.y);  d[6] = f2bf(f1.z);  d[7] = f2bf(f1.w);
      d[8] = f2bf(f2.x);  d[9] = f2bf(f2.y);  d[10] = f2bf(f2.z); d[11] = f2bf(f2.w);
      d[12] = f2bf(f3.x); d[13] = f2bf(f3.y); d[14] = f2bf(f3.z); d[15] = f2bf(f3.w);
    }
    // stage B (transposed): W[kk+r][nc0+c] -> tB[c][r], r=tid>>3, c0=(tid&7)*8
    {
      int r = tid >> 3, c0 = (tid & 7) * 8;
      const float* src = W + (size_t)(kk + r) * 256 + nc0 + c0;
      f32x4 g0 = *(const f32x4*)(src);
      f32x4 g1 = *(const f32x4*)(src + 4);
      tB[c0 + 0][r] = f2bf(g0.x); tB[c0 + 1][r] = f2bf(g0.y);
      tB[c0 + 2][r] = f2bf(g0.z); tB[c0 + 3][r] = f2bf(g0.w);
      tB[c0 + 4][r] = f2bf(g1.x); tB[c0 + 5][r] = f2bf(g1.y);
      tB[c0 + 6][r] = f2bf(g1.z); tB[c0 + 7][r] = f2bf(g1.w);
    }
    __syncthreads();
    FragAB af[4], bf[2];
#pragma unroll
    for (int mt = 0; mt < 4; mt++) {
      const unsigned short* p = &tA[wm * 64 + mt * 16 + l16][q * 8];
      af[mt].u[0] = *(const u16x4*)p;
      af[mt].u[1] = *(const u16x4*)(p + 4);
    }
#pragma unroll
    for (int nt = 0; nt < 2; nt++) {
      const unsigned short* p = &tB[wn * 32 + nt * 16 + l16][q * 8];
      bf[nt].u[0] = *(const u16x4*)p;
      bf[nt].u[1] = *(const u16x4*)(p + 4);
    }
#pragma unroll
    for (int mt = 0; mt < 4; mt++)
#pragma unroll
      for (int nt = 0; nt < 2; nt++)
        acc[mt][nt] = __builtin_amdgcn_mfma_f32_16x16x32_bf16(
            af[mt].f, bf[nt].f, acc[mt][nt], 0, 0, 0);
    __syncthreads();
  }
  // epilogue: C/D 16x16 layout col=lane&15, row=q*4+reg -> write HT transposed
#pragma unroll
  for (int mt = 0; mt < 4; mt++)
#pragma unroll
    for (int nt = 0; nt < 2; nt++) {
      int hrow = nb * 64 + wn * 32 + nt * 16 + l16;
      int j0 = rb * 128 + wm * 64 + mt * 16 + q * 4;
      u16x4 hv;
      hv.x = f2bf(acc[mt][nt].x);
      hv.y = f2bf(acc[mt][nt].y);
      hv.z = f2bf(acc[mt][nt].z);
      hv.w = f2bf(acc[mt][nt].w);
      *(u16x4*)(HT + (size_t)hrow * NN + j0) = hv;  // 8B store, j0 % 4 == 0
    }
}

// ---------- kernel 3: out += sum_k (adj==k) @ H_k ----------
// BM=128, BN=256 (full width: adj read exactly once), BK=32, splitK=4.
// 512 thr = 8 waves, wave grid 2(m) x 4(n), wave tile 64x64, MFMA 32x32x16 bf16.
// grid = 256 blocks; ks = bx&3 matches XCD round-robin so each XCD's L2 holds
// its 3.15MB HT k-slice.
__global__ __launch_bounds__(512) void k_agg(const int* __restrict__ adj,
                                             const unsigned short* __restrict__ HT,
                                             float* __restrict__ out) {
  int bx = blockIdx.x;
  int ks = bx & 3, rb = bx >> 2;
  int tid = threadIdx.x, lane = tid & 63;
  int wv = tid >> 6;
  int wm = wv >> 2, wn = wv & 3;
  int q = lane >> 5, l32 = lane & 31;

  __shared__ unsigned short msk[3][128][36];  // (adj==k) bf16 masks, 72B rows

  f32x16 acc[2][2];
  acc[0][0] = (f32x16)0.0f;
  acc[0][1] = (f32x16)0.0f;
  acc[1][0] = (f32x16)0.0f;
  acc[1][1] = (f32x16)0.0f;

  // staging map: r = tid>>2 (0..127), col group (tid&3)*8
  int sr = tid >> 2, scg = tid & 3;
  const int* ap = adj + (size_t)(rb * 128 + sr) * NN + ks * 2048 + scg * 8;

  // B base pointers (per type, per n-subtile): HT row = ty*256 + n
  const unsigned short* bbase[3][2];
#pragma unroll
  for (int ty = 0; ty < 3; ty++)
#pragma unroll
    for (int nt = 0; nt < 2; nt++)
      bbase[ty][nt] = HT + (size_t)(ty * 256 + wn * 64 + nt * 32 + l32) * NN +
                      ks * 2048 + q * 8;

  i32x4 a0 = *(const i32x4*)ap;
  i32x4 a1 = *(const i32x4*)(ap + 4);

  for (int step = 0; step < 64; step++) {
    // build 3 one-hot bf16 masks from the prefetched adj tile
    {
      int av[8] = {a0.x, a0.y, a0.z, a0.w, a1.x, a1.y, a1.z, a1.w};
#pragma unroll
      for (int ty = 0; ty < 3; ty++) {
        u16x4 lo, hi;
        lo.x = (av[0] == ty + 1) ? 0x3F80 : 0;
        lo.y = (av[1] == ty + 1) ? 0x3F80 : 0;
        lo.z = (av[2] == ty + 1) ? 0x3F80 : 0;
        lo.w = (av[3] == ty + 1) ? 0x3F80 : 0;
        hi.x = (av[4] == ty + 1) ? 0x3F80 : 0;
        hi.y = (av[5] == ty + 1) ? 0x3F80 : 0;
        hi.z = (av[6] == ty + 1) ? 0x3F80 : 0;
        hi.w = (av[7] == ty + 1) ? 0x3F80 : 0;
        unsigned short* d = &msk[ty][sr][scg * 8];
        *(u16x4*)d = lo;
        *(u16x4*)(d + 4) = hi;
      }
    }
    __syncthreads();
    // prefetch next adj tile (overlaps MFMA below)
    if (step < 63) {
      ap += 32;
      a0 = *(const i32x4*)ap;
      a1 = *(const i32x4*)(ap + 4);
    }
    int koff = step * 32;
#pragma unroll
    for (int kh = 0; kh < 2; kh++)
#pragma unroll
      for (int ty = 0; ty < 3; ty++) {
        FragAB af[2], bf[2];
#pragma unroll
        for (int mt = 0; mt < 2; mt++) {
          const unsigned short* p =
              &msk[ty][wm * 64 + mt * 32 + l32][kh * 16 + q * 8];
          af[mt].u[0] = *(const u16x4*)p;  // 2 x b64 (72B rows -> no 16B align)
          af[mt].u[1] = *(const u16x4*)(p + 4);
        }
#pragma unroll
        for (int nt = 0; nt < 2; nt++) {
          const unsigned short* p = bbase[ty][nt] + koff + kh * 16;
          bf[nt].v = *(const i32x4*)p;  // 16B global load (L2-resident HT)
        }
        acc[0][0] = __builtin_amdgcn_mfma_f32_32x32x16_bf16(af[0].f, bf[0].f,
                                                            acc[0][0], 0, 0, 0);
        acc[0][1] = __builtin_amdgcn_mfma_f32_32x32x16_bf16(af[0].f, bf[1].f,
                                                            acc[0][1], 0, 0, 0);
        acc[1][0] = __builtin_amdgcn_mfma_f32_32x32x16_bf16(af[1].f, bf[0].f,
                                                            acc[1][0], 0, 0, 0);
        acc[1][1] = __builtin_amdgcn_mfma_f32_32x32x16_bf16(af[1].f, bf[1].f,
                                                            acc[1][1], 0, 0, 0);
      }
    __syncthreads();
  }
  // epilogue: C/D 32x32 layout col=lane&31, row=(reg&3)+8*(reg>>2)+4*q
#pragma unroll
  for (int mt = 0; mt < 2; mt++)
#pragma unroll
    for (int nt = 0; nt < 2; nt++) {
      int colbase = wn * 64 + nt * 32 + l32;
      int rowb = rb * 128 + wm * 64 + mt * 32 + 4 * q;
#pragma unroll
      for (int r = 0; r < 16; r++) {
        int row = rowb + (r & 3) + 8 * (r >> 2);
        atomicAdd(out + (size_t)row * 256 + colbase, acc[mt][nt][r]);
      }
    }
}

extern "C" void kernel_launch(void* const* d_in, const int* in_sizes, int n_in,
                              void* d_out, int out_size, void* d_ws,
                              size_t ws_size, hipStream_t stream) {
  const float* V = (const float*)d_in[0];
  const int* adj = (const int*)d_in[1];
  const float* w1 = (const float*)d_in[2];
  const float* w2 = (const float*)d_in[3];
  const float* w3 = (const float*)d_in[4];
  const float* bias = (const float*)d_in[5];
  float* out = (float*)d_out;
  unsigned short* HT = (unsigned short*)d_ws;  // 768*8192*2 = 12.6 MB

  k_bias<<<dim3(NN), dim3(256), 0, stream>>>(bias, out);
  k_transform<<<dim3(768), dim3(256), 0, stream>>>(V, w1, w2, w3, HT);
  k_agg<<<dim3(256), dim3(512), 0, stream>>>(adj, HT, out);
}

// Round 2
// 577.469 us; speedup vs baseline: 1.0158x; 1.0158x over previous
//
#include <hip/hip_runtime.h>

typedef __attribute__((ext_vector_type(4))) float f32x4;
typedef __attribute__((ext_vector_type(16))) float f32x16;
typedef __attribute__((ext_vector_type(4))) unsigned short u16x4;
typedef __attribute__((ext_vector_type(4))) int i32x4;
typedef __attribute__((ext_vector_type(8))) __bf16 bf16x8;

union FragAB {
  u16x4 u[2];
  i32x4 v;
  bf16x8 f;
};

static __device__ __forceinline__ unsigned short f2bf(float x) {
  union { float f; unsigned u; } v;
  v.f = x;
  unsigned r = v.u + 0x7FFFu + ((v.u >> 16) & 1u);  // round-to-nearest-even
  return (unsigned short)(r >> 16);
}

#define NN 8192

// ---------- kernel 1: d_out = bias (broadcast) ----------
__global__ __launch_bounds__(256) void k_bias(const float* __restrict__ bias,
                                              float* __restrict__ out) {
  out[(size_t)blockIdx.x * 256 + threadIdx.x] = bias[threadIdx.x];
}

// ---------- kernel 2: Bp = (V @ Wcat)^T in k-blocked layout, bf16 ----------
// Bp element (ty, n, j) at  ty*2097152 + (j>>4)*4096 + n*16 + (j&15).
// This makes k_agg's B-fragment loads fully coalesced (1 KB/wave/instr).
// GEMM M=8192(j) x N=768(3*256) x K=256(c). BM=128, BN=64, BK=32.
// 256 thr = 4 waves, wave grid 2x2, wave tile 64x32, MFMA 16x16x32 bf16.
__global__ __launch_bounds__(256) void k_transform(
    const float* __restrict__ V, const float* __restrict__ w1,
    const float* __restrict__ w2, const float* __restrict__ w3,
    unsigned short* __restrict__ Bp) {
  int bx = blockIdx.x;
  int rb = bx & 63;   // j tile of 128
  int nb = bx >> 6;   // 0..11 (64-wide col tile within 768)
  const float* W = (nb < 4) ? w1 : (nb < 8) ? w2 : w3;
  int nc0 = (nb & 3) * 64;
  int tid = threadIdx.x;
  int lane = tid & 63;
  int wv = tid >> 6;
  int wm = wv >> 1, wn = wv & 1;
  int q = lane >> 4, l16 = lane & 15;

  __shared__ unsigned short tA[128][36];  // V tile bf16, padded (72B rows)
  __shared__ unsigned short tB[64][36];   // W tile transposed [n][c]

  f32x4 acc[4][2];
#pragma unroll
  for (int i = 0; i < 4; i++)
#pragma unroll
    for (int j = 0; j < 2; j++) acc[i][j] = (f32x4)0.0f;

  for (int kk = 0; kk < 256; kk += 32) {
    // stage A: V[rb*128 + r][kk + c], r=tid>>1, c0=(tid&1)*16, 16 floats/thread
    {
      int r = tid >> 1, c0 = (tid & 1) * 16;
      const float* src = V + (size_t)(rb * 128 + r) * 256 + kk + c0;
      f32x4 f0 = *(const f32x4*)(src + 0);
      f32x4 f1 = *(const f32x4*)(src + 4);
      f32x4 f2 = *(const f32x4*)(src + 8);
      f32x4 f3 = *(const f32x4*)(src + 12);
      unsigned short* d = &tA[r][c0];
      d[0] = f2bf(f0.x);  d[1] = f2bf(f0.y);  d[2] = f2bf(f0.z);  d[3] = f2bf(f0.w);
      d[4] = f2bf(f1.x);  d[5] = f2bf(f1.y);  d[6] = f2bf(f1.z);  d[7] = f2bf(f1.w);
      d[8] = f2bf(f2.x);  d[9] = f2bf(f2.y);  d[10] = f2bf(f2.z); d[11] = f2bf(f2.w);
      d[12] = f2bf(f3.x); d[13] = f2bf(f3.y); d[14] = f2bf(f3.z); d[15] = f2bf(f3.w);
    }
    // stage B (transposed): W[kk+r][nc0+c] -> tB[c][r], r=tid>>3, c0=(tid&7)*8
    {
      int r = tid >> 3, c0 = (tid & 7) * 8;
      const float* src = W + (size_t)(kk + r) * 256 + nc0 + c0;
      f32x4 g0 = *(const f32x4*)(src);
      f32x4 g1 = *(const f32x4*)(src + 4);
      tB[c0 + 0][r] = f2bf(g0.x); tB[c0 + 1][r] = f2bf(g0.y);
      tB[c0 + 2][r] = f2bf(g0.z); tB[c0 + 3][r] = f2bf(g0.w);
      tB[c0 + 4][r] = f2bf(g1.x); tB[c0 + 5][r] = f2bf(g1.y);
      tB[c0 + 6][r] = f2bf(g1.z); tB[c0 + 7][r] = f2bf(g1.w);
    }
    __syncthreads();
    FragAB af[4], bf[2];
#pragma unroll
    for (int mt = 0; mt < 4; mt++) {
      const unsigned short* p = &tA[wm * 64 + mt * 16 + l16][q * 8];
      af[mt].u[0] = *(const u16x4*)p;
      af[mt].u[1] = *(const u16x4*)(p + 4);
    }
#pragma unroll
    for (int nt = 0; nt < 2; nt++) {
      const unsigned short* p = &tB[wn * 32 + nt * 16 + l16][q * 8];
      bf[nt].u[0] = *(const u16x4*)p;
      bf[nt].u[1] = *(const u16x4*)(p + 4);
    }
#pragma unroll
    for (int mt = 0; mt < 4; mt++)
#pragma unroll
      for (int nt = 0; nt < 2; nt++)
        acc[mt][nt] = __builtin_amdgcn_mfma_f32_16x16x32_bf16(
            af[mt].f, bf[nt].f, acc[mt][nt], 0, 0, 0);
    __syncthreads();
  }
  // epilogue: C/D 16x16 layout col=lane&15 (=n), row=q*4+reg (=j within tile).
  // Write to Bp blocked layout: idx = ty*2097152 + (j>>4)*4096 + n*16 + (j&15).
  int ty = nb >> 2;
#pragma unroll
  for (int mt = 0; mt < 4; mt++)
#pragma unroll
    for (int nt = 0; nt < 2; nt++) {
      int n = (nb & 3) * 64 + wn * 32 + nt * 16 + l16;
      int j0 = rb * 128 + wm * 64 + mt * 16 + q * 4;  // j0&15 == q*4
      u16x4 hv;
      hv.x = f2bf(acc[mt][nt].x);
      hv.y = f2bf(acc[mt][nt].y);
      hv.z = f2bf(acc[mt][nt].z);
      hv.w = f2bf(acc[mt][nt].w);
      size_t idx = (size_t)ty * 2097152 + (size_t)(j0 >> 4) * 4096 + n * 16 + (j0 & 15);
      *(u16x4*)(Bp + idx) = hv;  // 8B store, idx%4==0
    }
}

// ---------- kernel 3: out += sum_k (adj==k) @ H_k ----------
// BM=128, BN=256 (full width: adj read exactly once), BK=32, splitK=4.
// 512 thr = 8 waves, wave grid 2(m) x 4(n), wave tile 64x64, MFMA 32x32x16 bf16.
// grid = 256 blocks; ks = bx&3 matches the XCD round-robin so each XCD's L2
// holds its 3.1MB Bp k-slice. B-frags load DIRECT from global (Bp blocked
// layout -> one contiguous 1KB segment per wave load; no gather, no LDS).
__global__ __launch_bounds__(512) void k_agg(const int* __restrict__ adj,
                                             const unsigned short* __restrict__ Bp,
                                             float* __restrict__ out) {
  int bx = blockIdx.x;
  int ks = bx & 3, rb = bx >> 2;
  int tid = threadIdx.x, lane = tid & 63;
  int wv = tid >> 6;
  int wm = wv >> 2, wn = wv & 3;
  int q = lane >> 5, l32 = lane & 31;

  __shared__ unsigned short msk[3][128][36];  // (adj==k) bf16 masks, 72B rows

  f32x16 acc[2][2];
  acc[0][0] = (f32x16)0.0f;
  acc[0][1] = (f32x16)0.0f;
  acc[1][0] = (f32x16)0.0f;
  acc[1][1] = (f32x16)0.0f;

  // adj staging map: r = tid>>2 (0..127), col group (tid&3)*8
  int sr = tid >> 2, scg = tid & 3;
  const int* ap = adj + (size_t)(rb * 128 + sr) * NN + ks * 2048 + scg * 8;

  // B base pointers (per type, per n-subtile), element offset within step:
  // idx = ty*2097152 + (ks*128 + step*2 + kh)*4096 + n*16 + q*8
  const unsigned short* bb[3][2];
#pragma unroll
  for (int ty = 0; ty < 3; ty++)
#pragma unroll
    for (int nt = 0; nt < 2; nt++) {
      int n = wn * 64 + nt * 32 + l32;
      bb[ty][nt] = Bp + (size_t)ty * 2097152 + (size_t)ks * 524288 + n * 16 + q * 8;
    }

  i32x4 a0 = *(const i32x4*)ap;
  i32x4 a1 = *(const i32x4*)(ap + 4);

  for (int step = 0; step < 64; step++) {
    // build 3 one-hot bf16 masks from the prefetched adj tile
    {
      int av[8] = {a0.x, a0.y, a0.z, a0.w, a1.x, a1.y, a1.z, a1.w};
#pragma unroll
      for (int ty = 0; ty < 3; ty++) {
        u16x4 lo, hi;
        lo.x = (av[0] == ty + 1) ? 0x3F80 : 0;
        lo.y = (av[1] == ty + 1) ? 0x3F80 : 0;
        lo.z = (av[2] == ty + 1) ? 0x3F80 : 0;
        lo.w = (av[3] == ty + 1) ? 0x3F80 : 0;
        hi.x = (av[4] == ty + 1) ? 0x3F80 : 0;
        hi.y = (av[5] == ty + 1) ? 0x3F80 : 0;
        hi.z = (av[6] == ty + 1) ? 0x3F80 : 0;
        hi.w = (av[7] == ty + 1) ? 0x3F80 : 0;
        unsigned short* d = &msk[ty][sr][scg * 8];
        *(u16x4*)d = lo;
        *(u16x4*)(d + 4) = hi;
      }
    }
    __syncthreads();
    // prefetch next adj tile (overlaps MFMA below)
    if (step < 63) {
      ap += 32;
      a0 = *(const i32x4*)ap;
      a1 = *(const i32x4*)(ap + 4);
    }
    int boff = step * 8192;  // element offset: step*2*4096
#pragma unroll
    for (int kh = 0; kh < 2; kh++)
#pragma unroll
      for (int ty = 0; ty < 3; ty++) {
        FragAB af[2], bf[2];
#pragma unroll
        for (int mt = 0; mt < 2; mt++) {
          const unsigned short* p =
              &msk[ty][wm * 64 + mt * 32 + l32][kh * 16 + q * 8];
          af[mt].u[0] = *(const u16x4*)p;
          af[mt].u[1] = *(const u16x4*)(p + 4);
        }
#pragma unroll
        for (int nt = 0; nt < 2; nt++) {
          const unsigned short* p = bb[ty][nt] + boff + kh * 4096;
          bf[nt].v = *(const i32x4*)p;  // coalesced: wave covers 1KB contig
        }
        acc[0][0] = __builtin_amdgcn_mfma_f32_32x32x16_bf16(af[0].f, bf[0].f,
                                                            acc[0][0], 0, 0, 0);
        acc[0][1] = __builtin_amdgcn_mfma_f32_32x32x16_bf16(af[0].f, bf[1].f,
                                                            acc[0][1], 0, 0, 0);
        acc[1][0] = __builtin_amdgcn_mfma_f32_32x32x16_bf16(af[1].f, bf[0].f,
                                                            acc[1][0], 0, 0, 0);
        acc[1][1] = __builtin_amdgcn_mfma_f32_32x32x16_bf16(af[1].f, bf[1].f,
                                                            acc[1][1], 0, 0, 0);
      }
    __syncthreads();
  }
  // epilogue: C/D 32x32 layout col=lane&31, row=(reg&3)+8*(reg>>2)+4*q
#pragma unroll
  for (int mt = 0; mt < 2; mt++)
#pragma unroll
    for (int nt = 0; nt < 2; nt++) {
      int colbase = wn * 64 + nt * 32 + l32;
      int rowb = rb * 128 + wm * 64 + mt * 32 + 4 * q;
#pragma unroll
      for (int r = 0; r < 16; r++) {
        int row = rowb + (r & 3) + 8 * (r >> 2);
        atomicAdd(out + (size_t)row * 256 + colbase, acc[mt][nt][r]);
      }
    }
}

extern "C" void kernel_launch(void* const* d_in, const int* in_sizes, int n_in,
                              void* d_out, int out_size, void* d_ws,
                              size_t ws_size, hipStream_t stream) {
  const float* V = (const float*)d_in[0];
  const int* adj = (const int*)d_in[1];
  const float* w1 = (const float*)d_in[2];
  const float* w2 = (const float*)d_in[3];
  const float* w3 = (const float*)d_in[4];
  const float* bias = (const float*)d_in[5];
  float* out = (float*)d_out;
  unsigned short* Bp = (unsigned short*)d_ws;  // 768*8192*2 = 12.6 MB

  k_bias<<<dim3(NN), dim3(256), 0, stream>>>(bias, out);
  k_transform<<<dim3(768), dim3(256), 0, stream>>>(V, w1, w2, w3, Bp);
  k_agg<<<dim3(256), dim3(512), 0, stream>>>(adj, Bp, out);
}

// Round 3
// 488.323 us; speedup vs baseline: 1.2013x; 1.1826x over previous
//
#include <hip/hip_runtime.h>

typedef __attribute__((ext_vector_type(4))) float f32x4;
typedef __attribute__((ext_vector_type(16))) float f32x16;
typedef __attribute__((ext_vector_type(4))) unsigned short u16x4;
typedef __attribute__((ext_vector_type(4))) int i32x4;
typedef __attribute__((ext_vector_type(8))) __bf16 bf16x8;

union FragAB {
  u16x4 u[2];
  i32x4 v;
  bf16x8 f;
};

static __device__ __forceinline__ unsigned short f2bf(float x) {
  union { float f; unsigned u; } v;
  v.f = x;
  unsigned r = v.u + 0x7FFFu + ((v.u >> 16) & 1u);  // round-to-nearest-even
  return (unsigned short)(r >> 16);
}

#define NN 8192

// ---------- kernel 1: d_out = bias (broadcast) ----------
__global__ __launch_bounds__(256) void k_bias(const float* __restrict__ bias,
                                              float* __restrict__ out) {
  out[(size_t)blockIdx.x * 256 + threadIdx.x] = bias[threadIdx.x];
}

// ---------- kernel 2: Bp = (V @ Wcat)^T in k-blocked layout, bf16 ----------
// Bp element (ty, n, j) at  ty*2097152 + (j>>4)*4096 + n*16 + (j&15).
__global__ __launch_bounds__(256) void k_transform(
    const float* __restrict__ V, const float* __restrict__ w1,
    const float* __restrict__ w2, const float* __restrict__ w3,
    unsigned short* __restrict__ Bp) {
  int bx = blockIdx.x;
  int rb = bx & 63;   // j tile of 128
  int nb = bx >> 6;   // 0..11 (64-wide col tile within 768)
  const float* W = (nb < 4) ? w1 : (nb < 8) ? w2 : w3;
  int nc0 = (nb & 3) * 64;
  int tid = threadIdx.x;
  int lane = tid & 63;
  int wv = tid >> 6;
  int wm = wv >> 1, wn = wv & 1;
  int q = lane >> 4, l16 = lane & 15;

  __shared__ unsigned short tA[128][36];  // V tile bf16, padded (72B rows)
  __shared__ unsigned short tB[64][36];   // W tile transposed [n][c]

  f32x4 acc[4][2];
#pragma unroll
  for (int i = 0; i < 4; i++)
#pragma unroll
    for (int j = 0; j < 2; j++) acc[i][j] = (f32x4)0.0f;

  for (int kk = 0; kk < 256; kk += 32) {
    {
      int r = tid >> 1, c0 = (tid & 1) * 16;
      const float* src = V + (size_t)(rb * 128 + r) * 256 + kk + c0;
      f32x4 f0 = *(const f32x4*)(src + 0);
      f32x4 f1 = *(const f32x4*)(src + 4);
      f32x4 f2 = *(const f32x4*)(src + 8);
      f32x4 f3 = *(const f32x4*)(src + 12);
      unsigned short* d = &tA[r][c0];
      d[0] = f2bf(f0.x);  d[1] = f2bf(f0.y);  d[2] = f2bf(f0.z);  d[3] = f2bf(f0.w);
      d[4] = f2bf(f1.x);  d[5] = f2bf(f1.y);  d[6] = f2bf(f1.z);  d[7] = f2bf(f1.w);
      d[8] = f2bf(f2.x);  d[9] = f2bf(f2.y);  d[10] = f2bf(f2.z); d[11] = f2bf(f2.w);
      d[12] = f2bf(f3.x); d[13] = f2bf(f3.y); d[14] = f2bf(f3.z); d[15] = f2bf(f3.w);
    }
    {
      int r = tid >> 3, c0 = (tid & 7) * 8;
      const float* src = W + (size_t)(kk + r) * 256 + nc0 + c0;
      f32x4 g0 = *(const f32x4*)(src);
      f32x4 g1 = *(const f32x4*)(src + 4);
      tB[c0 + 0][r] = f2bf(g0.x); tB[c0 + 1][r] = f2bf(g0.y);
      tB[c0 + 2][r] = f2bf(g0.z); tB[c0 + 3][r] = f2bf(g0.w);
      tB[c0 + 4][r] = f2bf(g1.x); tB[c0 + 5][r] = f2bf(g1.y);
      tB[c0 + 6][r] = f2bf(g1.z); tB[c0 + 7][r] = f2bf(g1.w);
    }
    __syncthreads();
    FragAB af[4], bf[2];
#pragma unroll
    for (int mt = 0; mt < 4; mt++) {
      const unsigned short* p = &tA[wm * 64 + mt * 16 + l16][q * 8];
      af[mt].u[0] = *(const u16x4*)p;
      af[mt].u[1] = *(const u16x4*)(p + 4);
    }
#pragma unroll
    for (int nt = 0; nt < 2; nt++) {
      const unsigned short* p = &tB[wn * 32 + nt * 16 + l16][q * 8];
      bf[nt].u[0] = *(const u16x4*)p;
      bf[nt].u[1] = *(const u16x4*)(p + 4);
    }
#pragma unroll
    for (int mt = 0; mt < 4; mt++)
#pragma unroll
      for (int nt = 0; nt < 2; nt++)
        acc[mt][nt] = __builtin_amdgcn_mfma_f32_16x16x32_bf16(
            af[mt].f, bf[nt].f, acc[mt][nt], 0, 0, 0);
    __syncthreads();
  }
  int ty = nb >> 2;
#pragma unroll
  for (int mt = 0; mt < 4; mt++)
#pragma unroll
    for (int nt = 0; nt < 2; nt++) {
      int n = (nb & 3) * 64 + wn * 32 + nt * 16 + l16;
      int j0 = rb * 128 + wm * 64 + mt * 16 + q * 4;
      u16x4 hv;
      hv.x = f2bf(acc[mt][nt].x);
      hv.y = f2bf(acc[mt][nt].y);
      hv.z = f2bf(acc[mt][nt].z);
      hv.w = f2bf(acc[mt][nt].w);
      size_t idx = (size_t)ty * 2097152 + (size_t)(j0 >> 4) * 4096 + n * 16 + (j0 & 15);
      *(u16x4*)(Bp + idx) = hv;
    }
}

// ---------- kernel 3: out += sum_k (adj==k) @ H_k ----------
// v3: BM=64, BN=256, BK=32, splitK=8 -> 1024 blocks (4 blocks'-work/CU).
// 256 thr = 4 waves, each wave one 64x64 tile (wn = wave id), MFMA 32x32x16.
// Double-buffered mask LDS -> ONE barrier per step; adj register-prefetched
// one step ahead; all 12 B-loads + 12 A-frag LDS reads batch-issued before
// the 24 MFMAs (ILP). ks = bx&7 -> each XCD L2 caches one 1.58MB Bp k-slice.
__global__ __launch_bounds__(256) void k_agg(const int* __restrict__ adj,
                                             const unsigned short* __restrict__ Bp,
                                             float* __restrict__ out) {
  int bx = blockIdx.x;
  int ks = bx & 7, rb = bx >> 3;
  int tid = threadIdx.x, lane = tid & 63;
  int wn = tid >> 6;  // 0..3: which 64-col slab
  int q = lane >> 5, l32 = lane & 31;

  __shared__ unsigned short msk[2][3][64][36];  // double-buffered masks

  f32x16 acc[2][2];
  acc[0][0] = (f32x16)0.0f;
  acc[0][1] = (f32x16)0.0f;
  acc[1][0] = (f32x16)0.0f;
  acc[1][1] = (f32x16)0.0f;

  // adj staging map: 64 rows x 32 k per step; thread: row sr, k-group scg*8
  int sr = tid >> 2, scg = tid & 3;
  const int* ap = adj + (size_t)(rb * 64 + sr) * NN + ks * 1024 + scg * 8;

  // B base pointers: Bp + ty*2097152 + ks*262144 + n*16 + q*8 (+ (step*2+kh)*4096)
  const unsigned short* bb[3][2];
#pragma unroll
  for (int ty = 0; ty < 3; ty++)
#pragma unroll
    for (int nt = 0; nt < 2; nt++) {
      int n = wn * 64 + nt * 32 + l32;
      bb[ty][nt] = Bp + (size_t)ty * 2097152 + (size_t)ks * 262144 + n * 16 + q * 8;
    }

  // --- prologue: build msk[0] from step0, prefetch step1 into regs ---
  i32x4 a0 = *(const i32x4*)ap;
  i32x4 a1 = *(const i32x4*)(ap + 4);
  ap += 32;
  {
    int av[8] = {a0.x, a0.y, a0.z, a0.w, a1.x, a1.y, a1.z, a1.w};
#pragma unroll
    for (int ty = 0; ty < 3; ty++) {
      u16x4 lo, hi;
      lo.x = (av[0] == ty + 1) ? 0x3F80 : 0;
      lo.y = (av[1] == ty + 1) ? 0x3F80 : 0;
      lo.z = (av[2] == ty + 1) ? 0x3F80 : 0;
      lo.w = (av[3] == ty + 1) ? 0x3F80 : 0;
      hi.x = (av[4] == ty + 1) ? 0x3F80 : 0;
      hi.y = (av[5] == ty + 1) ? 0x3F80 : 0;
      hi.z = (av[6] == ty + 1) ? 0x3F80 : 0;
      hi.w = (av[7] == ty + 1) ? 0x3F80 : 0;
      unsigned short* d = &msk[0][ty][sr][scg * 8];
      *(u16x4*)d = lo;
      *(u16x4*)(d + 4) = hi;
    }
  }
  a0 = *(const i32x4*)ap;
  a1 = *(const i32x4*)(ap + 4);
  ap += 32;
  __syncthreads();

  for (int step = 0; step < 32; step++) {
    int buf = step & 1;
    // --- batch-issue all 12 B loads (coalesced 1KB/wave each, L2-resident) ---
    FragAB bv[2][3][2];
    size_t soff = (size_t)step * 8192;
#pragma unroll
    for (int kh = 0; kh < 2; kh++)
#pragma unroll
      for (int ty = 0; ty < 3; ty++)
#pragma unroll
        for (int nt = 0; nt < 2; nt++)
          bv[kh][ty][nt].v = *(const i32x4*)(bb[ty][nt] + soff + kh * 4096);
    // --- batch-issue all 12 A-frag LDS reads (2x b64 each, 2-way = free) ---
    FragAB af[2][3][2];
#pragma unroll
    for (int kh = 0; kh < 2; kh++)
#pragma unroll
      for (int ty = 0; ty < 3; ty++)
#pragma unroll
        for (int mt = 0; mt < 2; mt++) {
          const unsigned short* p = &msk[buf][ty][mt * 32 + l32][kh * 16 + q * 8];
          af[kh][ty][mt].u[0] = *(const u16x4*)p;
          af[kh][ty][mt].u[1] = *(const u16x4*)(p + 4);
        }
    // --- 24 MFMAs ---
#pragma unroll
    for (int kh = 0; kh < 2; kh++)
#pragma unroll
      for (int ty = 0; ty < 3; ty++) {
        acc[0][0] = __builtin_amdgcn_mfma_f32_32x32x16_bf16(
            af[kh][ty][0].f, bv[kh][ty][0].f, acc[0][0], 0, 0, 0);
        acc[0][1] = __builtin_amdgcn_mfma_f32_32x32x16_bf16(
            af[kh][ty][0].f, bv[kh][ty][1].f, acc[0][1], 0, 0, 0);
        acc[1][0] = __builtin_amdgcn_mfma_f32_32x32x16_bf16(
            af[kh][ty][1].f, bv[kh][ty][0].f, acc[1][0], 0, 0, 0);
        acc[1][1] = __builtin_amdgcn_mfma_f32_32x32x16_bf16(
            af[kh][ty][1].f, bv[kh][ty][1].f, acc[1][1], 0, 0, 0);
      }
    // --- build next step's masks into the other buffer, refill prefetch ---
    if (step < 31) {
      int av[8] = {a0.x, a0.y, a0.z, a0.w, a1.x, a1.y, a1.z, a1.w};
#pragma unroll
      for (int ty = 0; ty < 3; ty++) {
        u16x4 lo, hi;
        lo.x = (av[0] == ty + 1) ? 0x3F80 : 0;
        lo.y = (av[1] == ty + 1) ? 0x3F80 : 0;
        lo.z = (av[2] == ty + 1) ? 0x3F80 : 0;
        lo.w = (av[3] == ty + 1) ? 0x3F80 : 0;
        hi.x = (av[4] == ty + 1) ? 0x3F80 : 0;
        hi.y = (av[5] == ty + 1) ? 0x3F80 : 0;
        hi.z = (av[6] == ty + 1) ? 0x3F80 : 0;
        hi.w = (av[7] == ty + 1) ? 0x3F80 : 0;
        unsigned short* d = &msk[buf ^ 1][ty][sr][scg * 8];
        *(u16x4*)d = lo;
        *(u16x4*)(d + 4) = hi;
      }
      if (step < 30) {
        a0 = *(const i32x4*)ap;
        a1 = *(const i32x4*)(ap + 4);
        ap += 32;
      }
    }
    __syncthreads();
  }
  // epilogue: C/D 32x32 layout col=lane&31, row=(reg&3)+8*(reg>>2)+4*q
#pragma unroll
  for (int mt = 0; mt < 2; mt++)
#pragma unroll
    for (int nt = 0; nt < 2; nt++) {
      int colbase = wn * 64 + nt * 32 + l32;
      int rowb = rb * 64 + mt * 32 + 4 * q;
#pragma unroll
      for (int r = 0; r < 16; r++) {
        int row = rowb + (r & 3) + 8 * (r >> 2);
        atomicAdd(out + (size_t)row * 256 + colbase, acc[mt][nt][r]);
      }
    }
}

extern "C" void kernel_launch(void* const* d_in, const int* in_sizes, int n_in,
                              void* d_out, int out_size, void* d_ws,
                              size_t ws_size, hipStream_t stream) {
  const float* V = (const float*)d_in[0];
  const int* adj = (const int*)d_in[1];
  const float* w1 = (const float*)d_in[2];
  const float* w2 = (const float*)d_in[3];
  const float* w3 = (const float*)d_in[4];
  const float* bias = (const float*)d_in[5];
  float* out = (float*)d_out;
  unsigned short* Bp = (unsigned short*)d_ws;  // 768*8192*2 = 12.6 MB

  k_bias<<<dim3(NN), dim3(256), 0, stream>>>(bias, out);
  k_transform<<<dim3(768), dim3(256), 0, stream>>>(V, w1, w2, w3, Bp);
  k_agg<<<dim3(1024), dim3(256), 0, stream>>>(adj, Bp, out);
}